// Round 1
// baseline (128.219 us; speedup 1.0000x reference)
//
#include <hip/hip_runtime.h>
#include <stdint.h>

// TargetTokenEncoder: histogram-stats -> MLP(14->256 GELU ->256) fused.
// B=65536 rows, S=128 support, C=10 classes, D=256.
// Strategy: tiny prep kernel converts w1 (K-padded to 16) and w2 to bf16,
// TRANSPOSED so MFMA B-fragments are 16B-contiguous per lane. Main kernel:
// 64 rows/block, 256 threads (4 waves: 2 in M x 2 in N), 32x32x16 bf16 MFMA.

#define SSUP 128
#define DD   256

typedef __attribute__((ext_vector_type(8)))  short bf16x8;   // 8 bf16 = 4 VGPRs
typedef __attribute__((ext_vector_type(16))) float f32x16;   // C/D for 32x32 MFMA

__device__ __forceinline__ unsigned f2bf_u(float f) {
    union { float f; unsigned u; } v; v.f = f;
    // round-to-nearest-even bf16 (no NaN inputs here)
    return (v.u + 0x7FFFu + ((v.u >> 16) & 1u)) >> 16;
}
__device__ __forceinline__ unsigned pk2(float a, float b) {
    return f2bf_u(a) | (f2bf_u(b) << 16);
}

// tanh-form GELU; |dev from exact erf-GELU| < 0.003 << tolerance.
// Saturates correctly at large |x| (exp underflow/overflow -> x or 0).
__device__ __forceinline__ float gelu_f(float x) {
    float z = 0.7978845608028654f * x * (1.0f + 0.044715f * x * x);
    float e = __expf(-2.0f * z);
    float th = 2.0f / (1.0f + e) - 1.0f;
    return 0.5f * x * (1.0f + th);
}

// w1t[n][kk] (256 x 16, kk>=14 zero), w2t[n][k] (256 x 256) — both bf16,
// transposed so B-frag (n=lane&31, k=(lane>>5)*8+j) is a contiguous 16B load.
__global__ void prep_kernel(const float* __restrict__ w1,
                            const float* __restrict__ w2,
                            unsigned short* __restrict__ w1t,
                            unsigned short* __restrict__ w2t) {
    int tid = blockIdx.x * 256 + threadIdx.x;
    if (tid < DD * DD) {
        int n = tid >> 8, k = tid & 255;
        w2t[tid] = (unsigned short)f2bf_u(w2[k * DD + n]);
    } else {
        int t = tid - DD * DD;              // 0..4095
        int n = t >> 4, kk = t & 15;
        w1t[t] = (kk < 14) ? (unsigned short)f2bf_u(w1[kk * DD + n])
                           : (unsigned short)0;
    }
}

__global__ __launch_bounds__(256, 4)
void encoder_kernel(const int* __restrict__ y,
                    const float* __restrict__ b1,
                    const float* __restrict__ b2,
                    const unsigned short* __restrict__ w1t,
                    const unsigned short* __restrict__ w2t,
                    float* __restrict__ out) {
    __shared__ __align__(16) unsigned short stats_a[64][16];   // 2 KB, A of GEMM1
    __shared__ __align__(16) unsigned short h_lds[64][264];    // 33 KB (+8 pad)

    const int tid = threadIdx.x;
    const int r0 = blockIdx.x * 64;

    // ---------------- Phase 1: histogram + stats ----------------
    // 4 threads per row, 32 labels each; 10 counters (<=32) packed 6b in u64.
    const int rl = tid >> 2;     // local row 0..63
    const int q  = tid & 3;      // quarter of support set
    const int4* yp = (const int4*)(y + (size_t)(r0 + rl) * SSUP + q * 32);
    unsigned long long pkc = 0ull;
    #pragma unroll
    for (int i = 0; i < 8; ++i) {
        int4 v = yp[i];
        pkc += 1ull << (6 * v.x);
        pkc += 1ull << (6 * v.y);
        pkc += 1ull << (6 * v.z);
        pkc += 1ull << (6 * v.w);
    }
    float p[10]; float ent = 0.f, pmax = 0.f, nnz = 0.f;
    #pragma unroll
    for (int c = 0; c < 10; ++c) {
        int cc = (int)((pkc >> (6 * c)) & 63ull);
        cc += __shfl_xor(cc, 1);     // row's 4 threads are adjacent lanes
        cc += __shfl_xor(cc, 2);
        float pc = (float)cc * 0.0078125f;        // total is always 128
        p[c] = pc;
        nnz += (cc > 0) ? 1.0f : 0.0f;
        ent -= pc * __logf(pc + 1e-6f);           // 0*log(1e-6) = 0, safe
        pmax = fmaxf(pmax, pc);
    }
    if (q < 2) {  // stats row: [p0..p9, nnz, ent, 128, pmax, 0, 0] as bf16
        unsigned a0, a1, a2, a3;
        if (q == 0) { a0 = pk2(p[0], p[1]); a1 = pk2(p[2], p[3]);
                      a2 = pk2(p[4], p[5]); a3 = pk2(p[6], p[7]); }
        else        { a0 = pk2(p[8], p[9]); a1 = pk2(nnz, ent);
                      a2 = pk2(128.0f, pmax); a3 = 0u; }
        uint4 vv = make_uint4(a0, a1, a2, a3);
        *(uint4*)&stats_a[rl][q * 8] = vv;
    }
    __syncthreads();

    const int lane = tid & 63;
    const int wid  = tid >> 6;
    const int wm   = wid & 1;    // M half: rows 32*wm..+31
    const int wn   = wid >> 1;   // N half: cols 128*wn..+127
    const int l31  = lane & 31;
    const int lh   = lane >> 5;

    // ---------------- Phase 2: GEMM1 + GELU -> h_lds ----------------
    bf16x8 af1 = *(const bf16x8*)&stats_a[32 * wm + l31][lh * 8];
    #pragma unroll
    for (int t = 0; t < 4; ++t) {
        const int col = 128 * wn + 32 * t + l31;
        float bias = b1[col];
        f32x16 c;
        #pragma unroll
        for (int r = 0; r < 16; ++r) c[r] = bias;
        bf16x8 bf1 = *(const bf16x8*)&w1t[col * 16 + lh * 8];
        c = __builtin_amdgcn_mfma_f32_32x32x16_bf16(af1, bf1, c, 0, 0, 0);
        #pragma unroll
        for (int r = 0; r < 16; ++r) {
            int row = (r & 3) + 8 * (r >> 2) + 4 * lh;   // C/D row map (m74/m101)
            h_lds[32 * wm + row][col] = (unsigned short)f2bf_u(gelu_f(c[r]));
        }
    }
    __syncthreads();

    // ---------------- Phase 3: GEMM2 -> out ----------------
    f32x16 acc[4];
    #pragma unroll
    for (int t = 0; t < 4; ++t) {
        float bias = b2[128 * wn + 32 * t + l31];
        #pragma unroll
        for (int r = 0; r < 16; ++r) acc[t][r] = bias;
    }
    #pragma unroll 4
    for (int s = 0; s < 16; ++s) {
        bf16x8 afr = *(const bf16x8*)&h_lds[32 * wm + l31][s * 16 + lh * 8];
        #pragma unroll
        for (int t = 0; t < 4; ++t) {
            const int col = 128 * wn + 32 * t + l31;
            bf16x8 bfr = *(const bf16x8*)&w2t[(size_t)col * DD + s * 16 + lh * 8];
            acc[t] = __builtin_amdgcn_mfma_f32_32x32x16_bf16(afr, bfr, acc[t], 0, 0, 0);
        }
    }
    #pragma unroll
    for (int t = 0; t < 4; ++t) {
        const int col = 128 * wn + 32 * t + l31;
        #pragma unroll
        for (int r = 0; r < 16; ++r) {
            int row = (r & 3) + 8 * (r >> 2) + 4 * lh;
            out[(size_t)(r0 + 32 * wm + row) * DD + col] = acc[t][r];
        }
    }
}

extern "C" void kernel_launch(void* const* d_in, const int* in_sizes, int n_in,
                              void* d_out, int out_size, void* d_ws, size_t ws_size,
                              hipStream_t stream) {
    const int*   y  = (const int*)d_in[0];
    const float* w1 = (const float*)d_in[1];
    const float* b1 = (const float*)d_in[2];
    const float* w2 = (const float*)d_in[3];
    const float* b2 = (const float*)d_in[4];
    float* out = (float*)d_out;

    unsigned short* w2t = (unsigned short*)d_ws;        // 256*256 bf16
    unsigned short* w1t = w2t + DD * DD;                // 256*16 bf16

    prep_kernel<<<(DD * DD + DD * 16) / 256, 256, 0, stream>>>(w1, w2, w1t, w2t);

    const int nrows = in_sizes[0] / SSUP;               // 65536
    encoder_kernel<<<nrows / 64, 256, 0, stream>>>(y, b1, b2, w1t, w2t, out);
}

// Round 2
// 114.751 us; speedup vs baseline: 1.1174x; 1.1174x over previous
//
#include <hip/hip_runtime.h>
#include <stdint.h>

// TargetTokenEncoder: histogram-stats -> MLP(14->256 GELU ->256) fused.
// B=65536 rows, S=128 support, C=10 classes, D=256.
// R2: fragment-major bf16 weight layout (coalesced 1KB B-frag loads) and
// phase-3 split into two N-pass halves (acc 32 AGPR) to free VGPRs for
// load pipelining under __launch_bounds__(256,4).

#define SSUP 128
#define DD   256

typedef __attribute__((ext_vector_type(8)))  short bf16x8;   // 8 bf16 = 4 VGPRs
typedef __attribute__((ext_vector_type(16))) float f32x16;   // C/D for 32x32 MFMA

__device__ __forceinline__ unsigned f2bf_u(float f) {
    union { float f; unsigned u; } v; v.f = f;
    return (v.u + 0x7FFFu + ((v.u >> 16) & 1u)) >> 16;   // RNE, no NaNs here
}
__device__ __forceinline__ unsigned pk2(float a, float b) {
    return f2bf_u(a) | (f2bf_u(b) << 16);
}

// tanh-form GELU; |dev from exact erf-GELU| < 0.003 << tolerance.
__device__ __forceinline__ float gelu_f(float x) {
    float z = 0.7978845608028654f * x * (1.0f + 0.044715f * x * x);
    float e = __expf(-2.0f * z);
    float th = 2.0f / (1.0f + e) - 1.0f;
    return 0.5f * x * (1.0f + th);
}

// Fragment-major weights. B-frag (32x32x16): n = nt*32 + (l&31),
// k = s*16 + (l>>5)*8 + j. Stored so one lane's 8 shorts are contiguous and
// the 64 lanes of a frag are one 1KB segment:
//   w2f[((s*8 + nt)*64 + l)*8 + j] = bf16(w2[k*256 + n])   (s<16, nt<8)
//   w1f[(nt*64 + l)*8 + j]         = bf16(w1[kk*256 + n]), kk=(l>>5)*8+j, pad kk>=14
__global__ void prep_kernel(const float* __restrict__ w1,
                            const float* __restrict__ w2,
                            unsigned short* __restrict__ w1f,
                            unsigned short* __restrict__ w2f) {
    int tid = blockIdx.x * 256 + threadIdx.x;
    if (tid < 8192) {                       // w2f: one thread per (s,nt,lane)
        int l  = tid & 63;
        int nt = (tid >> 6) & 7;
        int s  = tid >> 9;
        int n  = nt * 32 + (l & 31);
        int k0 = s * 16 + (l >> 5) * 8;
        unsigned pk[4];
        #pragma unroll
        for (int h = 0; h < 4; ++h)
            pk[h] = pk2(w2[(size_t)(k0 + 2*h) * DD + n],
                        w2[(size_t)(k0 + 2*h + 1) * DD + n]);
        *(uint4*)&w2f[(size_t)tid * 8] = make_uint4(pk[0], pk[1], pk[2], pk[3]);
    } else if (tid < 8704) {                // w1f
        int idx = tid - 8192;
        int l   = idx & 63;
        int nt  = idx >> 6;
        int n   = nt * 32 + (l & 31);
        int kk0 = (l >> 5) * 8;
        unsigned pk[4];
        #pragma unroll
        for (int h = 0; h < 4; ++h) {
            int ka = kk0 + 2*h, kb = kk0 + 2*h + 1;
            float fa = (ka < 14) ? w1[(size_t)ka * DD + n] : 0.0f;
            float fb = (kb < 14) ? w1[(size_t)kb * DD + n] : 0.0f;
            pk[h] = pk2(fa, fb);
        }
        *(uint4*)&w1f[(size_t)idx * 8] = make_uint4(pk[0], pk[1], pk[2], pk[3]);
    }
}

__global__ __launch_bounds__(256, 4)
void encoder_kernel(const int* __restrict__ y,
                    const float* __restrict__ b1,
                    const float* __restrict__ b2,
                    const unsigned short* __restrict__ w1f,
                    const unsigned short* __restrict__ w2f,
                    float* __restrict__ out) {
    __shared__ __align__(16) unsigned short stats_a[64][16];   // 2 KB
    __shared__ __align__(16) unsigned short h_lds[64][264];    // 33 KB (+8 pad)

    const int tid = threadIdx.x;
    const int r0 = blockIdx.x * 64;

    // ---------------- Phase 1: histogram + stats ----------------
    // 4 threads/row; q-interleaved int4 so each 4-lane group reads 64B runs.
    const int rl = tid >> 2;
    const int q  = tid & 3;
    const int4* yp = (const int4*)(y + (size_t)(r0 + rl) * SSUP);
    unsigned long long pkc = 0ull;
    #pragma unroll
    for (int i = 0; i < 8; ++i) {
        int4 v = yp[i * 4 + q];
        pkc += 1ull << (6 * v.x);
        pkc += 1ull << (6 * v.y);
        pkc += 1ull << (6 * v.z);
        pkc += 1ull << (6 * v.w);
    }
    float p[10]; float ent = 0.f, pmax = 0.f, nnz = 0.f;
    #pragma unroll
    for (int c = 0; c < 10; ++c) {
        int cc = (int)((pkc >> (6 * c)) & 63ull);
        cc += __shfl_xor(cc, 1);
        cc += __shfl_xor(cc, 2);
        float pc = (float)cc * 0.0078125f;        // total is always 128
        p[c] = pc;
        nnz += (cc > 0) ? 1.0f : 0.0f;
        ent -= pc * __logf(pc + 1e-6f);
        pmax = fmaxf(pmax, pc);
    }
    if (q < 2) {
        unsigned a0, a1, a2, a3;
        if (q == 0) { a0 = pk2(p[0], p[1]); a1 = pk2(p[2], p[3]);
                      a2 = pk2(p[4], p[5]); a3 = pk2(p[6], p[7]); }
        else        { a0 = pk2(p[8], p[9]); a1 = pk2(nnz, ent);
                      a2 = pk2(128.0f, pmax); a3 = 0u; }
        *(uint4*)&stats_a[rl][q * 8] = make_uint4(a0, a1, a2, a3);
    }
    __syncthreads();

    const int lane = tid & 63;
    const int wid  = tid >> 6;
    const int wm   = wid & 1;    // M half: rows 32*wm..+31
    const int wn   = wid >> 1;   // N half: cols 128*wn..+127
    const int l31  = lane & 31;
    const int lh   = lane >> 5;

    // ---------------- Phase 2: GEMM1 + GELU -> h_lds ----------------
    bf16x8 af1 = *(const bf16x8*)&stats_a[32 * wm + l31][lh * 8];
    #pragma unroll
    for (int t = 0; t < 4; ++t) {
        const int nt  = wn * 4 + t;
        const int col = nt * 32 + l31;
        float bias = b1[col];
        f32x16 c;
        #pragma unroll
        for (int r = 0; r < 16; ++r) c[r] = bias;
        bf16x8 bf1 = *(const bf16x8*)&w1f[(size_t)(nt * 64 + lane) * 8];
        c = __builtin_amdgcn_mfma_f32_32x32x16_bf16(af1, bf1, c, 0, 0, 0);
        #pragma unroll
        for (int r = 0; r < 16; ++r) {
            int row = (r & 3) + 8 * (r >> 2) + 4 * lh;   // C/D row map (m74/m101)
            h_lds[32 * wm + row][col] = (unsigned short)f2bf_u(gelu_f(c[r]));
        }
    }
    __syncthreads();

    // ---------------- Phase 3: GEMM2 -> out, two N-pass halves ----------------
    #pragma unroll
    for (int pass = 0; pass < 2; ++pass) {
        const int t0 = 2 * pass;
        f32x16 acc[2];
        #pragma unroll
        for (int u = 0; u < 2; ++u) {
            float bias = b2[(wn * 4 + t0 + u) * 32 + l31];
            #pragma unroll
            for (int r = 0; r < 16; ++r) acc[u][r] = bias;
        }
        #pragma unroll
        for (int s = 0; s < 16; ++s) {
            bf16x8 afr = *(const bf16x8*)&h_lds[32 * wm + l31][s * 16 + lh * 8];
            #pragma unroll
            for (int u = 0; u < 2; ++u) {
                const int nt = wn * 4 + t0 + u;
                bf16x8 bfr = *(const bf16x8*)
                    &w2f[(size_t)((s * 8 + nt) * 64 + lane) * 8];
                acc[u] = __builtin_amdgcn_mfma_f32_32x32x16_bf16(afr, bfr, acc[u], 0, 0, 0);
            }
        }
        #pragma unroll
        for (int u = 0; u < 2; ++u) {
            const int col = (wn * 4 + t0 + u) * 32 + l31;
            #pragma unroll
            for (int r = 0; r < 16; ++r) {
                int row = (r & 3) + 8 * (r >> 2) + 4 * lh;
                out[(size_t)(r0 + 32 * wm + row) * DD + col] = acc[u][r];
            }
        }
    }
}

extern "C" void kernel_launch(void* const* d_in, const int* in_sizes, int n_in,
                              void* d_out, int out_size, void* d_ws, size_t ws_size,
                              hipStream_t stream) {
    const int*   y  = (const int*)d_in[0];
    const float* w1 = (const float*)d_in[1];
    const float* b1 = (const float*)d_in[2];
    const float* w2 = (const float*)d_in[3];
    const float* b2 = (const float*)d_in[4];
    float* out = (float*)d_out;

    unsigned short* w2f = (unsigned short*)d_ws;        // 65536 shorts (128 KB)
    unsigned short* w1f = w2f + 65536;                  // 4096 shorts (8 KB)

    prep_kernel<<<34, 256, 0, stream>>>(w1, w2, w1f, w2f);

    const int nrows = in_sizes[0] / SSUP;               // 65536
    encoder_kernel<<<nrows / 64, 256, 0, stream>>>(y, b1, b2, w1f, w2f, out);
}